// Round 6
// baseline (3277.049 us; speedup 1.0000x reference)
//
#include <hip/hip_runtime.h>

#define T_ 256
#define B_ 64
#define I_ 512
#define H_ 1024
#define O_ 512
#define K_ 8
#define RING 16
#define NLB 32          // loop worker blocks: each owns 32 hidden dims
#define SROWX 520       // LDS row stride (ushorts) for 512-col tiles
#define SROWH 1032      // LDS row stride (ushorts) for 1024-col tiles

typedef unsigned short u16;
typedef __attribute__((ext_vector_type(8))) short short8;
typedef __attribute__((ext_vector_type(4))) float f32x4;
typedef __attribute__((ext_vector_type(4))) int   i32x4;

// Static device buffers (rewritten every call before use).
__device__ u16   g_xbf [T_*B_*I_];          // x bf16, 16.8 MB
__device__ u16   g_Bg  [3072u*1536u];       // gate B-frags bf16 (K-major frag-linear)
__device__ u16   g_Bo  [512u*1024u];        // out  B-frags bf16
__device__ u16   g_hall[(T_+1)*B_*H_];      // h_{-1}..h_{255} bf16, 33.7 MB
__device__ float g_GX  [(size_t)T_*B_*3072];// x@Wx + b, fp32, 201 MB
__device__ float g_ring[RING*B_*H_];        // h history ring fp32 (block-private cols)
__device__ int   g_isbf16;
__device__ unsigned g_cnt, g_gen;           // barrier state (monotonic)

__device__ __forceinline__ float b2f(u16 u) {
  return __uint_as_float(((unsigned)u) << 16);
}
__device__ __forceinline__ u16 f2b(float f) {
  unsigned u = __float_as_uint(f);
  u += 0x7FFFu + ((u >> 16) & 1u);   // RNE
  return (u16)(u >> 16);
}
__device__ __forceinline__ float ldv(const void* p, size_t i, int isb) {
  return isb ? b2f(((const u16*)p)[i]) : ((const float*)p)[i];
}
__device__ __forceinline__ float fsig(float x) {
  return __builtin_amdgcn_rcpf(1.0f + __expf(-x));
}
__device__ __forceinline__ float ftanh(float x) {
  return 1.0f - 2.0f*__builtin_amdgcn_rcpf(1.0f + __expf(2.0f*x));
}

// device-coherent (L2-bypassing, write-through) 16B ops
__device__ __forceinline__ void coh_load16(i32x4& dst, const void* p) {
  asm volatile("global_load_dwordx4 %0, %1, off sc0 sc1"
               : "=v"(dst) : "v"(p) : "memory");
}
__device__ __forceinline__ void coh_store16(void* p, i32x4 d) {
  asm volatile("global_store_dwordx4 %0, %1, off sc0 sc1"
               :: "v"(p), "v"(d) : "memory");
}
__device__ __forceinline__ void wait_vm0() {
  asm volatile("s_waitcnt vmcnt(0)" ::: "memory");
}

// ---- probe dtype + reset barrier state ----
__global__ void probe_dtype(const u16* __restrict__ xs)
{
  if (threadIdx.x == 0 && blockIdx.x == 0) {
    int crazy = 0;
    for (int i = 0; i < 1024; i++) {
      const unsigned e = (xs[i] >> 7) & 0xFFu;
      if (e >= 0x86u || (e != 0u && e <= 0x69u)) crazy++;
    }
    g_isbf16 = (crazy < 100) ? 1 : 0;
    g_cnt = 0u;
    g_gen = 0u;
  }
}

// ---- prep: x -> bf16 ----
__global__ __launch_bounds__(256) void prep_x(const void* __restrict__ x)
{
  const int e = (blockIdx.x*256 + threadIdx.x) * 4;
  ushort4 u;
  if (g_isbf16) {
    u = *(const ushort4*)((const u16*)x + e);
  } else {
    float4 v = *(const float4*)((const float*)x + e);
    u.x = f2b(v.x); u.y = f2b(v.y); u.z = f2b(v.z); u.w = f2b(v.w);
  }
  *(ushort4*)&g_xbf[e] = u;
}

// ---- prep: pack gate weights B-frag-linear ----
// g_Bg[((ht*3+g)*48+ks)*512 + lane*8 + j] = Wcat[ks*32+(lane>>4)*8+j][g*H + ht*16 + (lane&15)]
__global__ __launch_bounds__(256) void prep_pack_g(const void* __restrict__ Wx,
                                                   const void* __restrict__ Wh)
{
  const int isb = g_isbf16;
  const int id  = blockIdx.x*256 + threadIdx.x;      // < 589824
  const int lane = id & 63;
  const int ks   = (id >> 6) % 48;
  const int g    = ((id >> 6) / 48) % 3;
  const int ht   = (id >> 6) / 144;
  const int c    = g*H_ + ht*16 + (lane & 15);
  const int kb   = ks*32 + (lane >> 4)*8;
  u16 tmp[8];
#pragma unroll
  for (int j = 0; j < 8; j++) {
    const int k = kb + j;
    const float v = (k < I_) ? ldv(Wx, (size_t)k*3072 + c, isb)
                             : ldv(Wh, (size_t)(k - I_)*3072 + c, isb);
    tmp[j] = f2b(v);
  }
  *(ushort4*)&g_Bg[(size_t)id*8]     = make_ushort4(tmp[0],tmp[1],tmp[2],tmp[3]);
  *(ushort4*)&g_Bg[(size_t)id*8 + 4] = make_ushort4(tmp[4],tmp[5],tmp[6],tmp[7]);
}

// ---- prep: pack Wo ----
__global__ __launch_bounds__(256) void prep_pack_o(const void* __restrict__ Wo)
{
  const int isb = g_isbf16;
  const int id  = blockIdx.x*256 + threadIdx.x;      // < 65536
  const int lane = id & 63;
  const int ks   = (id >> 6) & 31;
  const int ot   = id >> 11;
  const int c    = ot*16 + (lane & 15);
  const int kb   = ks*32 + (lane >> 4)*8;
  u16 tmp[8];
#pragma unroll
  for (int j = 0; j < 8; j++) tmp[j] = f2b(ldv(Wo, (size_t)(kb + j)*O_ + c, isb));
  *(ushort4*)&g_Bo[(size_t)id*8]     = make_ushort4(tmp[0],tmp[1],tmp[2],tmp[3]);
  *(ushort4*)&g_Bo[(size_t)id*8 + 4] = make_ushort4(tmp[4],tmp[5],tmp[6],tmp[7]);
}

// ---- prep: hidden_states -> ring slots 8..15 fp32; slot 7 -> g_hall[0] bf16 ----
__global__ __launch_bounds__(256) void prep_ring(const void* __restrict__ hs)
{
  const int e = (blockIdx.x*256 + threadIdx.x) * 4;   // < 524288
  float4 v; ushort4 u;
  if (g_isbf16) {
    u = *(const ushort4*)((const u16*)hs + e);
    v = make_float4(b2f(u.x), b2f(u.y), b2f(u.z), b2f(u.w));
  } else {
    v = *(const float4*)((const float*)hs + e);
    u.x = f2b(v.x); u.y = f2b(v.y); u.z = f2b(v.z); u.w = f2b(v.w);
  }
  *(float4*)&g_ring[(size_t)8*B_*H_ + e] = v;
  if (e >= 7*B_*H_) *(ushort4*)&g_hall[e - 7*B_*H_] = u;   // h_{-1}
}

// ---- pre-GEMM: GX[t,b,c] = x_t @ Wx + b  (fp32, bias folded) ----
__global__ __launch_bounds__(1024) void gx_gemm(const void* __restrict__ bvec)
{
  const int isb = g_isbf16;
  const int t  = blockIdx.x >> 2;
  const int cg = blockIdx.x & 3;
  const int tid = threadIdx.x, lane = tid & 63, w = tid >> 6;
  const int m = w & 3, sub = w >> 2;
  const int quad = lane >> 4, l15 = lane & 15;
  __shared__ u16 s[64*SROWX];

#pragma unroll
  for (int it = 0; it < 4; it++) {
    const int idx = it*1024 + tid;
    const int row = idx >> 6, col8 = idx & 63;
    *(short8*)&s[row*SROWX + col8*8] =
        *(const short8*)(g_xbf + ((size_t)t*64 + row)*512 + col8*8);
  }
  __syncthreads();

  const u16* bbase[12];
#pragma unroll
  for (int nt = 0; nt < 12; nt++) {
    const int ct = cg*48 + sub*12 + nt;           // [0,192)
    const int gate = ct >> 6, ht = ct & 63;
    bbase[nt] = g_Bg + ((size_t)(ht*3 + gate)*48)*512 + lane*8;
  }
  f32x4 acc[12];
#pragma unroll
  for (int nt = 0; nt < 12; nt++) acc[nt] = (f32x4){0.f,0.f,0.f,0.f};

  for (int ks = 0; ks < 16; ks++) {
    const short8 a = *(const short8*)&s[(m*16 + l15)*SROWX + ks*32 + quad*8];
#pragma unroll
    for (int nt = 0; nt < 12; nt++) {
      const short8 b = *(const short8*)(bbase[nt] + (size_t)ks*512);
      acc[nt] = __builtin_amdgcn_mfma_f32_16x16x32_bf16(a, b, acc[nt], 0, 0, 0);
    }
  }

#pragma unroll
  for (int nt = 0; nt < 12; nt++) {
    const int ct = cg*48 + sub*12 + nt;
    const int c  = ct*16 + l15;
    const float bias = ldv(bvec, c, isb);
#pragma unroll
    for (int r = 0; r < 4; r++) {
      const int b_row = m*16 + quad*4 + r;
      g_GX[((size_t)t*64 + b_row)*3072 + c] = acc[nt][r] + bias;
    }
  }
}

// ---- the sequential loop: gh = h_{t-1}@Wh, gates, h_t. 32 blocks x 512 thr ----
// R1 structure (proven): 8 waves = (2 ht-subtiles) x (4 k-quarters); Wh frags
// persistent in VGPRs; k-split partials reduced through LDS aliased into the
// dead h-stage buffer; epilogue operands loaded post-stage/pre-MFMA (R1
// placement — R4 proved cross-barrier prefetch regresses); monotonic RMW
// barrier. New vs R1: fast rcp/exp sigmoid/tanh only (R4-verified safe).
__global__ __launch_bounds__(512, 2) void mgruf_loop(const void* __restrict__ mp)
{
  const int tid = threadIdx.x, lane = tid & 63, w = tid >> 6, blk = blockIdx.x;
  const int q = w & 3, g = w >> 2;               // k-quarter, ht-sub (0..1)
  const int quad = lane >> 4, l15 = lane & 15;
  const int ht = blk*2 + g;
  const int hh = ht*16 + l15;
  __shared__ u16 s [64*SROWH];                   // h_{t-1} staged, 129 KB; partial alias after MFMA
  __shared__ u16 s2[64*32];                      // h_new transpose buf, 4 KB

  float wc[8];
  {
    const float alpha = 0.5f / (1.0f + __expf(-ldv(mp, hh, g_isbf16)));
    float cacc = alpha; float tmp[8]; tmp[0] = cacc;
#pragma unroll
    for (int i = 1; i < 8; i++) { cacc *= ((float)i + alpha)/(float)(i+1); tmp[i] = cacc; }
#pragma unroll
    for (int j = 0; j < 8; j++) wc[j] = tmp[7 - j];
  }

  // ---- persistent Wh fragments: this wave's k-quarter, all 3 gates (96 VGPR) ----
  const u16* pz = g_Bg + ((size_t)(ht*3 + 0)*48 + 16 + q*8)*512 + lane*8;
  const u16* pr = pz + (size_t)48*512;
  const u16* pn = pz + (size_t)96*512;
  short8 Bz[8], Br[8], Bn[8];
#pragma unroll
  for (int i = 0; i < 8; i++) {
    Bz[i] = *(const short8*)(pz + (size_t)i*512);
    Br[i] = *(const short8*)(pr + (size_t)i*512);
    Bn[i] = *(const short8*)(pn + (size_t)i*512);
  }

  unsigned mygen = 0;

  for (int t = 0; t < T_; t++) {
    // ---- coherent staging of h_{t-1} (sourced at/through L3; no L2 staleness) ----
    {
      i32x4 tmp[16];
      const u16* hsrc = g_hall + (size_t)t*B_*H_;
#pragma unroll
      for (int it = 0; it < 16; it++) {
        coh_load16(tmp[it], hsrc + (size_t)(it*512 + tid)*8);
      }
      wait_vm0();
#pragma unroll
      for (int it = 0; it < 16; it++) {
        const int idx = it*512 + tid;
        const int row = idx >> 7, col8 = idx & 127;
        *(i32x4*)&s[row*SROWH + col8*8] = tmp[it];
      }
    }
    __syncthreads();

    // hoisted epilogue operands (independent of staged h) — overlap with MFMA.
    // R1 placement: issued here, consumed this step, never cross the barrier.
    float gxv[3][4], rv[8][4];
#pragma unroll
    for (int r = 0; r < 4; r++) {
      const int b = q*16 + quad*4 + r;
      const size_t gxb = ((size_t)t*64 + b)*3072;
      gxv[0][r] = g_GX[gxb + hh];
      gxv[1][r] = g_GX[gxb + 1024 + hh];
      gxv[2][r] = g_GX[gxb + 2048 + hh];
#pragma unroll
      for (int j = 0; j < 8; j++) {
        const int sl = (t - 8 + j + 16) & 15;
        rv[j][r] = g_ring[((size_t)sl*B_ + b)*H_ + hh];
      }
    }

    // ---- MFMA: this wave's k-quarter over all 4 m-tiles, weights from regs ----
    f32x4 az[4], ar[4], an[4];
#pragma unroll
    for (int m = 0; m < 4; m++) {
      az[m] = (f32x4){0.f,0.f,0.f,0.f}; ar[m] = az[m]; an[m] = az[m];
    }
#pragma unroll
    for (int i = 0; i < 8; i++) {
      const int ks = q*8 + i;
#pragma unroll
      for (int m = 0; m < 4; m++) {
        const short8 a = *(const short8*)&s[(m*16 + l15)*SROWH + ks*32 + quad*8];
        az[m] = __builtin_amdgcn_mfma_f32_16x16x32_bf16(a, Bz[i], az[m], 0, 0, 0);
        ar[m] = __builtin_amdgcn_mfma_f32_16x16x32_bf16(a, Br[i], ar[m], 0, 0, 0);
        an[m] = __builtin_amdgcn_mfma_f32_16x16x32_bf16(a, Bn[i], an[m], 0, 0, 0);
      }
    }
    __syncthreads();   // all LDS A-reads done; safe to alias partials into s

    // partial write: region w, byte off = w*12288 + (gate*4+m)*1024 + lane*16
    // (skip m==q: consumed from own registers)
    {
      char* pbase = (char*)s + (size_t)w*12288 + lane*16;
#pragma unroll
      for (int m = 0; m < 4; m++) {
        if (m == q) continue;
        *(f32x4*)(pbase + (0*4 + m)*1024) = az[m];
        *(f32x4*)(pbase + (1*4 + m)*1024) = ar[m];
        *(f32x4*)(pbase + (2*4 + m)*1024) = an[m];
      }
    }
    __syncthreads();

    // reduce: sum the 4 k-quarter partials for m == q (this wave's epilogue rows)
    f32x4 sz = az[q], sr = ar[q], sn = an[q];
#pragma unroll
    for (int q2 = 0; q2 < 4; q2++) {
      if (q2 == q) continue;
      const char* rb = (const char*)s + (size_t)((g<<2)|q2)*12288 + lane*16;
      sz += *(const f32x4*)(rb + (0*4 + q)*1024);
      sr += *(const f32x4*)(rb + (1*4 + q)*1024);
      sn += *(const f32x4*)(rb + (2*4 + q)*1024);
    }

#pragma unroll
    for (int r = 0; r < 4; r++) {
      const int b = q*16 + quad*4 + r;
      const float z  = fsig(gxv[0][r] + sz[r]);
      const float rr = fsig(gxv[1][r] + sr[r]);
      const float nn = ftanh(gxv[2][r] + rr*sn[r]);
      float mem = 0.f;
#pragma unroll
      for (int j = 0; j < 8; j++) mem += wc[j] * rv[j][r];
      const float hnew = (1.f - z)*nn + z*mem;
      g_ring[((size_t)(t & 15)*B_ + b)*H_ + hh] = hnew;   // block-private cols, cached
      s2[b*32 + g*16 + l15] = f2b(hnew);
    }
    __syncthreads();                       // s2 complete; all ds_reads of s done

    // write-through publish of this block's 4 KB h-slice (16B chunks)
    if (tid < 256) {
      const int row = tid >> 2, c8 = tid & 3;
      const i32x4 d = *(const i32x4*)&s2[row*32 + c8*8];
      u16* dst = g_hall + (size_t)(t + 1)*B_*H_ + (size_t)row*1024 + blk*32 + c8*8;
      coh_store16(dst, d);
    }
    wait_vm0();                            // own stores at coherence point
    __syncthreads();                       // all waves' stores drained

    // ---- relaxed grid barrier (monotonic count; proven primitive) ----
    if (tid == 0) {
      const unsigned arr = __hip_atomic_fetch_add(&g_cnt, 1u, __ATOMIC_RELAXED,
                                                  __HIP_MEMORY_SCOPE_AGENT);
      if (arr == (mygen + 1u)*NLB - 1u) {  // monotonic count: no reset race
        __hip_atomic_store(&g_gen, mygen + 1u, __ATOMIC_RELAXED,
                           __HIP_MEMORY_SCOPE_AGENT);
      } else {
        while (__hip_atomic_load(&g_gen, __ATOMIC_RELAXED,
                                 __HIP_MEMORY_SCOPE_AGENT) <= mygen)
          __builtin_amdgcn_s_sleep(1);
      }
    }
    mygen++;
    __syncthreads();
  }
}

// ---- fallback loop step (no barrier; one launch per t; dispatch-boundary coherence) ----
__global__ __launch_bounds__(512, 1) void mgruf_loop_step(int t, const void* __restrict__ mp)
{
  const int tid = threadIdx.x, lane = tid & 63, w = tid >> 6, blk = blockIdx.x;
  const int m = w & 3, g = w >> 2;
  const int quad = lane >> 4, l15 = lane & 15;
  const int ht = blk*2 + g;
  const int hh = ht*16 + l15;
  __shared__ u16 s[64*SROWH];

  float wc[8];
  {
    const float alpha = 0.5f / (1.0f + __expf(-ldv(mp, hh, g_isbf16)));
    float cacc = alpha; float tmp[8]; tmp[0] = cacc;
#pragma unroll
    for (int i = 1; i < 8; i++) { cacc *= ((float)i + alpha)/(float)(i+1); tmp[i] = cacc; }
#pragma unroll
    for (int j = 0; j < 8; j++) wc[j] = tmp[7 - j];
  }
  const u16* pz = g_Bg + ((size_t)(ht*3 + 0)*48 + 16)*512 + lane*8;
  const u16* pr = pz + (size_t)48*512;
  const u16* pn = pz + (size_t)96*512;

#pragma unroll
  for (int it = 0; it < 16; it++) {
    const int idx = it*512 + tid;
    const int row = idx >> 7, col8 = idx & 127;
    *(short8*)&s[row*SROWH + col8*8] =
        *(const short8*)(g_hall + (size_t)t*B_*H_ + row*1024 + col8*8);
  }
  __syncthreads();

  f32x4 az = {0.f,0.f,0.f,0.f}, ar = az, anh = az;
#pragma unroll 8
  for (int ks = 0; ks < 32; ks++) {
    const short8 a  = *(const short8*)&s[(m*16 + l15)*SROWH + ks*32 + quad*8];
    const short8 bz = *(const short8*)(pz + (size_t)ks*512);
    const short8 br = *(const short8*)(pr + (size_t)ks*512);
    const short8 bn = *(const short8*)(pn + (size_t)ks*512);
    az  = __builtin_amdgcn_mfma_f32_16x16x32_bf16(a, bz, az, 0, 0, 0);
    ar  = __builtin_amdgcn_mfma_f32_16x16x32_bf16(a, br, ar, 0, 0, 0);
    anh = __builtin_amdgcn_mfma_f32_16x16x32_bf16(a, bn, anh, 0, 0, 0);
  }

#pragma unroll
  for (int r = 0; r < 4; r++) {
    const int b = m*16 + quad*4 + r;
    const size_t gxb = ((size_t)t*64 + b)*3072;
    const float gz = g_GX[gxb + hh];
    const float gr = g_GX[gxb + 1024 + hh];
    const float gn = g_GX[gxb + 2048 + hh];
    const float z  = 1.f / (1.f + __expf(-(gz + az[r])));
    const float rr = 1.f / (1.f + __expf(-(gr + ar[r])));
    const float nn = tanhf(gn + rr*anh[r]);
    float mem = 0.f;
#pragma unroll
    for (int j = 0; j < 8; j++) {
      const int sl = (t - 8 + j + 16) & 15;
      mem += wc[j] * g_ring[((size_t)sl*B_ + b)*H_ + hh];
    }
    const float hnew = (1.f - z)*nn + z*mem;
    g_ring[((size_t)(t & 15)*B_ + b)*H_ + hh] = hnew;
    g_hall[(size_t)(t + 1)*B_*H_ + (size_t)b*H_ + hh] = f2b(hnew);
  }
}

// ---- post-GEMM: out[t] = h_t @ Wo + bo.  grid 256 (one t each), 1024 thr ----
__global__ __launch_bounds__(1024) void out_gemm(const void* __restrict__ bov,
                                                 void* __restrict__ out)
{
  const int isb = g_isbf16;
  const int t = blockIdx.x;
  const int tid = threadIdx.x, lane = tid & 63, w = tid >> 6;
  const int m = w & 3, sub = w >> 2;
  const int quad = lane >> 4, l15 = lane & 15;
  __shared__ u16 s[64*SROWH];

#pragma unroll
  for (int it = 0; it < 8; it++) {
    const int idx = it*1024 + tid;
    const int row = idx >> 7, col8 = idx & 127;
    *(short8*)&s[row*SROWH + col8*8] =
        *(const short8*)(g_hall + (size_t)(t + 1)*B_*H_ + row*1024 + col8*8);
  }
  __syncthreads();

  f32x4 acc[8];
#pragma unroll
  for (int nt = 0; nt < 8; nt++) acc[nt] = (f32x4){0.f,0.f,0.f,0.f};

  for (int ks = 0; ks < 32; ks++) {
    const short8 a = *(const short8*)&s[(m*16 + l15)*SROWH + ks*32 + quad*8];
#pragma unroll
    for (int nt = 0; nt < 8; nt++) {
      const short8 b = *(const short8*)(g_Bo + ((size_t)(sub*8 + nt)*32 + ks)*512 + lane*8);
      acc[nt] = __builtin_amdgcn_mfma_f32_16x16x32_bf16(a, b, acc[nt], 0, 0, 0);
    }
  }

#pragma unroll
  for (int nt = 0; nt < 8; nt++) {
    const int oc = (sub*8 + nt)*16 + l15;
    const float bias = ldv(bov, oc, isb);
#pragma unroll
    for (int r = 0; r < 4; r++) {
      const int b = m*16 + quad*4 + r;
      const float v = acc[nt][r] + bias;
      const size_t idx = ((size_t)t*B_ + b)*O_ + oc;
      if (isb) ((u16*)out)[idx] = f2b(v);
      else     ((float*)out)[idx] = v;
    }
  }
}

// ---- H_fin from ring: 512 blocks x 256 thr x 4 elems = 524288 (exact cover) ----
__global__ __launch_bounds__(256) void hfin_kernel(void* __restrict__ out)
{
  const int isb = g_isbf16;
  const int i = blockIdx.x*256 + threadIdx.x;   // < 131072
  const int e   = i*4;                          // < 524288
  const int j   = e >> 16;                      // / (B*H)
  const int rem = e & 65535;
  const int sl  = (T_ - K_ + j) & 15;
  const float4 v = *(const float4*)&g_ring[(size_t)sl*B_*H_ + rem];
  if (isb) {
    ushort4 o4; o4.x = f2b(v.x); o4.y = f2b(v.y); o4.z = f2b(v.z); o4.w = f2b(v.w);
    *(ushort4*)((u16*)out + (size_t)T_*B_*O_ + e) = o4;
  } else {
    *(float4*)((float*)out + (size_t)T_*B_*O_ + e) = v;
  }
}

extern "C" void kernel_launch(void* const* d_in, const int* in_sizes, int n_in,
                              void* d_out, int out_size, void* d_ws, size_t ws_size,
                              hipStream_t stream)
{
  const void* x  = d_in[0];
  const void* hs = d_in[1];
  const void* Wx = d_in[2];
  const void* Wh = d_in[3];
  const void* bv = d_in[4];
  const void* Wo = d_in[5];
  const void* bo = d_in[6];
  const void* mp = d_in[7];
  void* out = d_out;

  probe_dtype<<<dim3(1), dim3(64), 0, stream>>>((const u16*)x);
  prep_x     <<<dim3(8192), dim3(256), 0, stream>>>(x);
  prep_pack_g<<<dim3(2304), dim3(256), 0, stream>>>(Wx, Wh);
  prep_pack_o<<<dim3(256),  dim3(256), 0, stream>>>(Wo);
  prep_ring  <<<dim3(512),  dim3(256), 0, stream>>>(hs);
  gx_gemm    <<<dim3(1024), dim3(1024), 0, stream>>>(bv);

  void* args[] = { (void*)&mp };
  hipError_t err = hipLaunchCooperativeKernel(
      reinterpret_cast<const void*>(&mgruf_loop),
      dim3(NLB), dim3(512), args, 0u, stream);
  if (err != hipSuccess) {
    for (int t = 0; t < T_; t++)
      mgruf_loop_step<<<dim3(NLB), dim3(512), 0, stream>>>(t, mp);
  }

  out_gemm   <<<dim3(256), dim3(1024), 0, stream>>>(bo, out);
  hfin_kernel<<<dim3(512), dim3(256), 0, stream>>>(out);
}

// Round 7
// 1360.026 us; speedup vs baseline: 2.4095x; 2.4095x over previous
//
#include <hip/hip_runtime.h>

#define T_ 256
#define B_ 64
#define I_ 512
#define H_ 1024
#define O_ 512
#define K_ 8
#define RING 16
#define NLB 32          // fallback loop blocks
#define GRPS 4          // batch groups (16 rows each)
#define NLBN (GRPS*32)  // main loop grid: 4 groups x 32 hidden-slots = 128
#define SROWX 520       // LDS row stride (ushorts) for 512-col tiles
#define SROWH 1032      // LDS row stride (ushorts) for 1024-col tiles (fallback/out)
#define SROW  1032      // loop h-stage row stride (u16)

typedef unsigned short u16;
typedef __attribute__((ext_vector_type(8))) short short8;
typedef __attribute__((ext_vector_type(4))) float f32x4;
typedef __attribute__((ext_vector_type(4))) int   i32x4;

// Static device buffers (rewritten every call before use).
__device__ u16   g_xbf [T_*B_*I_];          // x bf16, 16.8 MB
__device__ u16   g_Bg  [3072u*1536u];       // gate B-frags bf16 (K-major frag-linear)
__device__ u16   g_Bo  [512u*1024u];        // out  B-frags bf16
__device__ u16   g_hall[(T_+1)*B_*H_];      // h_{-1}..h_{255} bf16, 33.7 MB
__device__ float g_GX  [(size_t)T_*B_*3072];// x@Wx + b, fp32, 201 MB
__device__ float g_ring[RING*B_*H_];        // h ring fp32 (init + final dump + fallback)
__device__ int   g_isbf16;
__device__ unsigned g_gcnt[GRPS*32];        // per-group barrier counters (128B stride)
__device__ unsigned g_ggen[GRPS*32];        // per-group barrier generations

__device__ __forceinline__ float b2f(u16 u) {
  return __uint_as_float(((unsigned)u) << 16);
}
__device__ __forceinline__ u16 f2b(float f) {
  unsigned u = __float_as_uint(f);
  u += 0x7FFFu + ((u >> 16) & 1u);   // RNE
  return (u16)(u >> 16);
}
__device__ __forceinline__ float ldv(const void* p, size_t i, int isb) {
  return isb ? b2f(((const u16*)p)[i]) : ((const float*)p)[i];
}
__device__ __forceinline__ float fsig(float x) {
  return __builtin_amdgcn_rcpf(1.0f + __expf(-x));
}
__device__ __forceinline__ float ftanh(float x) {
  return 1.0f - 2.0f*__builtin_amdgcn_rcpf(1.0f + __expf(2.0f*x));
}

// device-coherent (L2-bypassing, write-through) 16B ops — proven primitives
__device__ __forceinline__ void coh_load16(i32x4& dst, const void* p) {
  asm volatile("global_load_dwordx4 %0, %1, off sc0 sc1"
               : "=v"(dst) : "v"(p) : "memory");
}
__device__ __forceinline__ void coh_store16(void* p, i32x4 d) {
  asm volatile("global_store_dwordx4 %0, %1, off sc0 sc1"
               :: "v"(p), "v"(d) : "memory");
}
__device__ __forceinline__ void wait_vm0() {
  asm volatile("s_waitcnt vmcnt(0)" ::: "memory");
}

// ---- probe dtype + reset barrier state ----
__global__ void probe_dtype(const u16* __restrict__ xs)
{
  const int tid = threadIdx.x;
  if (tid == 0 && blockIdx.x == 0) {
    int crazy = 0;
    for (int i = 0; i < 1024; i++) {
      const unsigned e = (xs[i] >> 7) & 0xFFu;
      if (e >= 0x86u || (e != 0u && e <= 0x69u)) crazy++;
    }
    g_isbf16 = (crazy < 100) ? 1 : 0;
  }
  for (int i = tid; i < GRPS*32; i += 64) { g_gcnt[i] = 0u; g_ggen[i] = 0u; }
}

// ---- prep: x -> bf16 ----
__global__ __launch_bounds__(256) void prep_x(const void* __restrict__ x)
{
  const int e = (blockIdx.x*256 + threadIdx.x) * 4;
  ushort4 u;
  if (g_isbf16) {
    u = *(const ushort4*)((const u16*)x + e);
  } else {
    float4 v = *(const float4*)((const float*)x + e);
    u.x = f2b(v.x); u.y = f2b(v.y); u.z = f2b(v.z); u.w = f2b(v.w);
  }
  *(ushort4*)&g_xbf[e] = u;
}

// ---- prep: pack gate weights B-frag-linear ----
// g_Bg[((ht*3+g)*48+ks)*512 + lane*8 + j] = Wcat[ks*32+(lane>>4)*8+j][g*H + ht*16 + (lane&15)]
__global__ __launch_bounds__(256) void prep_pack_g(const void* __restrict__ Wx,
                                                   const void* __restrict__ Wh)
{
  const int isb = g_isbf16;
  const int id  = blockIdx.x*256 + threadIdx.x;      // < 589824
  const int lane = id & 63;
  const int ks   = (id >> 6) % 48;
  const int g    = ((id >> 6) / 48) % 3;
  const int ht   = (id >> 6) / 144;
  const int c    = g*H_ + ht*16 + (lane & 15);
  const int kb   = ks*32 + (lane >> 4)*8;
  u16 tmp[8];
#pragma unroll
  for (int j = 0; j < 8; j++) {
    const int k = kb + j;
    const float v = (k < I_) ? ldv(Wx, (size_t)k*3072 + c, isb)
                             : ldv(Wh, (size_t)(k - I_)*3072 + c, isb);
    tmp[j] = f2b(v);
  }
  *(ushort4*)&g_Bg[(size_t)id*8]     = make_ushort4(tmp[0],tmp[1],tmp[2],tmp[3]);
  *(ushort4*)&g_Bg[(size_t)id*8 + 4] = make_ushort4(tmp[4],tmp[5],tmp[6],tmp[7]);
}

// ---- prep: pack Wo ----
__global__ __launch_bounds__(256) void prep_pack_o(const void* __restrict__ Wo)
{
  const int isb = g_isbf16;
  const int id  = blockIdx.x*256 + threadIdx.x;      // < 65536
  const int lane = id & 63;
  const int ks   = (id >> 6) & 31;
  const int ot   = id >> 11;
  const int c    = ot*16 + (lane & 15);
  const int kb   = ks*32 + (lane >> 4)*8;
  u16 tmp[8];
#pragma unroll
  for (int j = 0; j < 8; j++) tmp[j] = f2b(ldv(Wo, (size_t)(kb + j)*O_ + c, isb));
  *(ushort4*)&g_Bo[(size_t)id*8]     = make_ushort4(tmp[0],tmp[1],tmp[2],tmp[3]);
  *(ushort4*)&g_Bo[(size_t)id*8 + 4] = make_ushort4(tmp[4],tmp[5],tmp[6],tmp[7]);
}

// ---- prep: hidden_states -> ring slots 8..15 fp32; slot 7 -> g_hall[0] bf16 ----
__global__ __launch_bounds__(256) void prep_ring(const void* __restrict__ hs)
{
  const int e = (blockIdx.x*256 + threadIdx.x) * 4;   // < 524288
  float4 v; ushort4 u;
  if (g_isbf16) {
    u = *(const ushort4*)((const u16*)hs + e);
    v = make_float4(b2f(u.x), b2f(u.y), b2f(u.z), b2f(u.w));
  } else {
    v = *(const float4*)((const float*)hs + e);
    u.x = f2b(v.x); u.y = f2b(v.y); u.z = f2b(v.z); u.w = f2b(v.w);
  }
  *(float4*)&g_ring[(size_t)8*B_*H_ + e] = v;
  if (e >= 7*B_*H_) *(ushort4*)&g_hall[e - 7*B_*H_] = u;   // h_{-1}
}

// ---- pre-GEMM: GX[t,b,c] = x_t @ Wx + b  (fp32, bias folded) ----
__global__ __launch_bounds__(1024) void gx_gemm(const void* __restrict__ bvec)
{
  const int isb = g_isbf16;
  const int t  = blockIdx.x >> 2;
  const int cg = blockIdx.x & 3;
  const int tid = threadIdx.x, lane = tid & 63, w = tid >> 6;
  const int m = w & 3, sub = w >> 2;
  const int quad = lane >> 4, l15 = lane & 15;
  __shared__ u16 s[64*SROWX];

#pragma unroll
  for (int it = 0; it < 4; it++) {
    const int idx = it*1024 + tid;
    const int row = idx >> 6, col8 = idx & 63;
    *(short8*)&s[row*SROWX + col8*8] =
        *(const short8*)(g_xbf + ((size_t)t*64 + row)*512 + col8*8);
  }
  __syncthreads();

  const u16* bbase[12];
#pragma unroll
  for (int nt = 0; nt < 12; nt++) {
    const int ct = cg*48 + sub*12 + nt;           // [0,192)
    const int gate = ct >> 6, ht = ct & 63;
    bbase[nt] = g_Bg + ((size_t)(ht*3 + gate)*48)*512 + lane*8;
  }
  f32x4 acc[12];
#pragma unroll
  for (int nt = 0; nt < 12; nt++) acc[nt] = (f32x4){0.f,0.f,0.f,0.f};

  for (int ks = 0; ks < 16; ks++) {
    const short8 a = *(const short8*)&s[(m*16 + l15)*SROWX + ks*32 + quad*8];
#pragma unroll
    for (int nt = 0; nt < 12; nt++) {
      const short8 b = *(const short8*)(bbase[nt] + (size_t)ks*512);
      acc[nt] = __builtin_amdgcn_mfma_f32_16x16x32_bf16(a, b, acc[nt], 0, 0, 0);
    }
  }

#pragma unroll
  for (int nt = 0; nt < 12; nt++) {
    const int ct = cg*48 + sub*12 + nt;
    const int c  = ct*16 + l15;
    const float bias = ldv(bvec, c, isb);
#pragma unroll
    for (int r = 0; r < 4; r++) {
      const int b_row = m*16 + quad*4 + r;
      g_GX[((size_t)t*64 + b_row)*3072 + c] = acc[nt][r] + bias;
    }
  }
}

// ---- main loop: 128 blocks = 4 batch-groups x 32 hidden-slots, 512 thr ----
// Block (grp,slot): 16 batch rows x 32 hidden cols. 8 waves each own 4 Wh
// k-steps x all 6 n-tiles; weights persistent in VGPRs (96/wave, proven
// layout). Exchange: per-group 32KB slab; per-group fan-in-32 monotonic RMW
// barrier (proven primitive, 4 independent instances). Ring fully in LDS.
// All cross-block data ops sc0 sc1 (proven). Bounded barrier spin: a
// residency surprise fails fast instead of hanging the container.
__global__ __launch_bounds__(512, 2) void mgruf_loop(const void* __restrict__ mp)
{
  const int tid = threadIdx.x, lane = tid & 63, w = tid >> 6, blk = blockIdx.x;
  const int grp = blk & 3, slot = blk >> 2;        // 4 groups x 32 slots
  const int quad = lane >> 4, l15 = lane & 15;
  const int erow = tid >> 5, ecol = tid & 31;      // epilogue row(0..15), col(0..31)
  const int tle = ecol >> 4, c16 = ecol & 15;
  const int bglob = grp*16 + erow;
  const int hh = slot*32 + ecol;

  __shared__ u16   s[16*SROW];          // 33 KB h-slab stage
  __shared__ float part[8*6*256];       // 48 KB k-partials
  __shared__ float ghbuf[6*256];        // 6 KB reduced gh
  __shared__ float ringl[16*512];       // 32 KB ring [slot16][row*32+col]
  __shared__ u16   s2[512];             // 1 KB publish buf

  const int isb = g_isbf16;

  // ---- persistent Wh fragments: wave w owns kh = w*4..w*4+3, 6 n-tiles ----
  short8 Bf[6][4];
#pragma unroll
  for (int tle2 = 0; tle2 < 2; tle2++)
#pragma unroll
    for (int gam = 0; gam < 3; gam++)
#pragma unroll
      for (int i = 0; i < 4; i++)
        Bf[gam*2 + tle2][i] = *(const short8*)(g_Bg +
            ((size_t)((slot*2 + tle2)*3 + gam)*48 + 16 + w*4 + i)*512 + lane*8);

  // GL weights for this thread's hidden dim
  float wc[8];
  {
    const float alpha = 0.5f / (1.0f + __expf(-ldv(mp, hh, isb)));
    float cacc = alpha; float t8[8]; t8[0] = cacc;
#pragma unroll
    for (int i = 1; i < 8; i++) { cacc *= ((float)i + alpha)/(float)(i + 1); t8[i] = cacc; }
#pragma unroll
    for (int j = 0; j < 8; j++) wc[j] = t8[7 - j];
  }

  // ring init: slots 8..15 = h_{-8..-1} for this block's (rows x cols)
#pragma unroll
  for (int j = 0; j < 8; j++)
    ringl[(8 + j)*512 + tid] = g_ring[(size_t)(8 + j)*B_*H_ + (size_t)bglob*H_ + hh];

  unsigned* const cnt = &g_gcnt[grp*32];
  unsigned* const gen = &g_ggen[grp*32];
  unsigned mygen = 0;

  for (int t = 0; t < T_; t++) {
    // ---- stage group h-slab (32KB contiguous): 4 x 16B coherent loads ----
    {
      i32x4 tmp[4];
      const u16* hsrc = g_hall + (size_t)t*B_*H_ + (size_t)grp*16*H_;
#pragma unroll
      for (int it = 0; it < 4; it++)
        coh_load16(tmp[it], hsrc + (size_t)(it*512 + tid)*8);
      wait_vm0();
#pragma unroll
      for (int it = 0; it < 4; it++) {
        const int idx = it*512 + tid;
        *(i32x4*)&s[(idx >> 7)*SROW + (idx & 127)*8] = tmp[it];
      }
    }
    __syncthreads();

    // GX operands (plain cached loads; read-only data, written pre-dispatch)
    const float* gp = g_GX + ((size_t)t*64 + bglob)*3072 + hh;
    const float gxz = gp[0];
    const float gxr = gp[1024];
    const float gxn = gp[2048];

    // ---- MFMA: wave w's 4 k-steps over 6 n-tiles, weights from regs ----
    f32x4 acc[6];
#pragma unroll
    for (int nt = 0; nt < 6; nt++) acc[nt] = (f32x4){0.f,0.f,0.f,0.f};
#pragma unroll
    for (int i = 0; i < 4; i++) {
      const short8 a = *(const short8*)&s[l15*SROW + (w*4 + i)*32 + quad*8];
#pragma unroll
      for (int nt = 0; nt < 6; nt++)
        acc[nt] = __builtin_amdgcn_mfma_f32_16x16x32_bf16(a, Bf[nt][i], acc[nt], 0, 0, 0);
    }
    {
      float* pb = part + (size_t)(w*6)*256 + lane*4;
#pragma unroll
      for (int nt = 0; nt < 6; nt++) *(f32x4*)(pb + nt*256) = acc[nt];
    }
    __syncthreads();

    // ---- k-reduce (waves 0..5, one n-tile each) -> ghbuf[nt][row][col16] ----
    if (w < 6) {
      f32x4 sum = (f32x4){0.f,0.f,0.f,0.f};
#pragma unroll
      for (int ww = 0; ww < 8; ww++)
        sum += *(const f32x4*)(part + (size_t)(ww*6 + w)*256 + lane*4);
#pragma unroll
      for (int r = 0; r < 4; r++)
        ghbuf[w*256 + (quad*4 + r)*16 + l15] = sum[r];
    }
    __syncthreads();

    // ---- epilogue: one (row,col) per thread; ring in LDS ----
    {
      const float gz = ghbuf[(0*2 + tle)*256 + erow*16 + c16];
      const float gr = ghbuf[(1*2 + tle)*256 + erow*16 + c16];
      const float gn = ghbuf[(2*2 + tle)*256 + erow*16 + c16];
      const float z  = fsig(gxz + gz);
      const float rr = fsig(gxr + gr);
      const float nn = ftanh(gxn + rr*gn);
      float mem = 0.f;
#pragma unroll
      for (int j = 0; j < 8; j++)
        mem += wc[j] * ringl[((t + 8 + j) & 15)*512 + tid];
      const float hnew = (1.f - z)*nn + z*mem;
      ringl[(t & 15)*512 + tid] = hnew;
      s2[tid] = f2b(hnew);
    }
    __syncthreads();

    // ---- publish 1KB h-slice (64 x 16B), coherent write-through ----
    if (tid < 64) {
      const i32x4 d = *(const i32x4*)&s2[tid*8];
      u16* dst = g_hall + (size_t)(t + 1)*B_*H_
               + (size_t)(grp*16 + (tid >> 2))*H_ + slot*32 + (tid & 3)*8;
      coh_store16(dst, d);
    }
    wait_vm0();                          // own stores at coherence point
    __syncthreads();                     // all waves' stores drained

    // ---- per-group barrier (proven monotonic RMW; bounded spin) ----
    if (t + 1 < T_) {
      if (tid == 0) {
        const unsigned arr = __hip_atomic_fetch_add(cnt, 1u, __ATOMIC_RELAXED,
                                                    __HIP_MEMORY_SCOPE_AGENT);
        if (arr == (mygen + 1u)*32u - 1u) {
          __hip_atomic_store(gen, mygen + 1u, __ATOMIC_RELAXED,
                             __HIP_MEMORY_SCOPE_AGENT);
        } else {
          int spins = 0;
          while (__hip_atomic_load(gen, __ATOMIC_RELAXED,
                                   __HIP_MEMORY_SCOPE_AGENT) <= mygen &&
                 spins < (1 << 14)) {
            __builtin_amdgcn_s_sleep(1);
            ++spins;
          }
          // on timeout: proceed (visible numerical failure, never a hang)
        }
      }
      mygen++;
      __syncthreads();
    }
  }

  // ---- final: dump ring slots 8..15 (= h_{248..255}) for hfin ----
#pragma unroll
  for (int j = 0; j < 8; j++)
    g_ring[(size_t)(8 + j)*B_*H_ + (size_t)bglob*H_ + hh] = ringl[(8 + j)*512 + tid];
}

// ---- fallback loop step (no barrier; one launch per t; dispatch-boundary coherence) ----
__global__ __launch_bounds__(512, 1) void mgruf_loop_step(int t, const void* __restrict__ mp)
{
  const int tid = threadIdx.x, lane = tid & 63, w = tid >> 6, blk = blockIdx.x;
  const int m = w & 3, g = w >> 2;
  const int quad = lane >> 4, l15 = lane & 15;
  const int ht = blk*2 + g;
  const int hh = ht*16 + l15;
  __shared__ u16 s[64*SROWH];

  float wc[8];
  {
    const float alpha = 0.5f / (1.0f + __expf(-ldv(mp, hh, g_isbf16)));
    float cacc = alpha; float tmp[8]; tmp[0] = cacc;
#pragma unroll
    for (int i = 1; i < 8; i++) { cacc *= ((float)i + alpha)/(float)(i+1); tmp[i] = cacc; }
#pragma unroll
    for (int j = 0; j < 8; j++) wc[j] = tmp[7 - j];
  }
  const u16* pz = g_Bg + ((size_t)(ht*3 + 0)*48 + 16)*512 + lane*8;
  const u16* pr = pz + (size_t)48*512;
  const u16* pn = pz + (size_t)96*512;

#pragma unroll
  for (int it = 0; it < 16; it++) {
    const int idx = it*512 + tid;
    const int row = idx >> 7, col8 = idx & 127;
    *(short8*)&s[row*SROWH + col8*8] =
        *(const short8*)(g_hall + (size_t)t*B_*H_ + row*1024 + col8*8);
  }
  __syncthreads();

  f32x4 az = {0.f,0.f,0.f,0.f}, ar = az, anh = az;
#pragma unroll 8
  for (int ks = 0; ks < 32; ks++) {
    const short8 a  = *(const short8*)&s[(m*16 + l15)*SROWH + ks*32 + quad*8];
    const short8 bz = *(const short8*)(pz + (size_t)ks*512);
    const short8 br = *(const short8*)(pr + (size_t)ks*512);
    const short8 bn = *(const short8*)(pn + (size_t)ks*512);
    az  = __builtin_amdgcn_mfma_f32_16x16x32_bf16(a, bz, az, 0, 0, 0);
    ar  = __builtin_amdgcn_mfma_f32_16x16x32_bf16(a, br, ar, 0, 0, 0);
    anh = __builtin_amdgcn_mfma_f32_16x16x32_bf16(a, bn, anh, 0, 0, 0);
  }

#pragma unroll
  for (int r = 0; r < 4; r++) {
    const int b = m*16 + quad*4 + r;
    const size_t gxb = ((size_t)t*64 + b)*3072;
    const float gz = g_GX[gxb + hh];
    const float gr = g_GX[gxb + 1024 + hh];
    const float gn = g_GX[gxb + 2048 + hh];
    const float z  = 1.f / (1.f + __expf(-(gz + az[r])));
    const float rr = 1.f / (1.f + __expf(-(gr + ar[r])));
    const float nn = tanhf(gn + rr*anh[r]);
    float mem = 0.f;
#pragma unroll
    for (int j = 0; j < 8; j++) {
      const int sl = (t - 8 + j + 16) & 15;
      mem += wc[j] * g_ring[((size_t)sl*B_ + b)*H_ + hh];
    }
    const float hnew = (1.f - z)*nn + z*mem;
    g_ring[((size_t)(t & 15)*B_ + b)*H_ + hh] = hnew;
    g_hall[(size_t)(t + 1)*B_*H_ + (size_t)b*H_ + hh] = f2b(hnew);
  }
}

// ---- post-GEMM: out[t] = h_t @ Wo + bo.  grid 256 (one t each), 1024 thr ----
__global__ __launch_bounds__(1024) void out_gemm(const void* __restrict__ bov,
                                                 void* __restrict__ out)
{
  const int isb = g_isbf16;
  const int t = blockIdx.x;
  const int tid = threadIdx.x, lane = tid & 63, w = tid >> 6;
  const int m = w & 3, sub = w >> 2;
  const int quad = lane >> 4, l15 = lane & 15;
  __shared__ u16 s[64*SROWH];

#pragma unroll
  for (int it = 0; it < 8; it++) {
    const int idx = it*1024 + tid;
    const int row = idx >> 7, col8 = idx & 127;
    *(short8*)&s[row*SROWH + col8*8] =
        *(const short8*)(g_hall + (size_t)(t + 1)*B_*H_ + row*1024 + col8*8);
  }
  __syncthreads();

  f32x4 acc[8];
#pragma unroll
  for (int nt = 0; nt < 8; nt++) acc[nt] = (f32x4){0.f,0.f,0.f,0.f};

  for (int ks = 0; ks < 32; ks++) {
    const short8 a = *(const short8*)&s[(m*16 + l15)*SROWH + ks*32 + quad*8];
#pragma unroll
    for (int nt = 0; nt < 8; nt++) {
      const short8 b = *(const short8*)(g_Bo + ((size_t)(sub*8 + nt)*32 + ks)*512 + lane*8);
      acc[nt] = __builtin_amdgcn_mfma_f32_16x16x32_bf16(a, b, acc[nt], 0, 0, 0);
    }
  }

#pragma unroll
  for (int nt = 0; nt < 8; nt++) {
    const int oc = (sub*8 + nt)*16 + l15;
    const float bias = ldv(bov, oc, isb);
#pragma unroll
    for (int r = 0; r < 4; r++) {
      const int b = m*16 + quad*4 + r;
      const float v = acc[nt][r] + bias;
      const size_t idx = ((size_t)t*B_ + b)*O_ + oc;
      if (isb) ((u16*)out)[idx] = f2b(v);
      else     ((float*)out)[idx] = v;
    }
  }
}

// ---- H_fin from ring: 512 blocks x 256 thr x 4 elems = 524288 (exact cover) ----
__global__ __launch_bounds__(256) void hfin_kernel(void* __restrict__ out)
{
  const int isb = g_isbf16;
  const int i = blockIdx.x*256 + threadIdx.x;   // < 131072
  const int e   = i*4;                          // < 524288
  const int j   = e >> 16;                      // / (B*H)
  const int rem = e & 65535;
  const int sl  = (T_ - K_ + j) & 15;
  const float4 v = *(const float4*)&g_ring[(size_t)sl*B_*H_ + rem];
  if (isb) {
    ushort4 o4; o4.x = f2b(v.x); o4.y = f2b(v.y); o4.z = f2b(v.z); o4.w = f2b(v.w);
    *(ushort4*)((u16*)out + (size_t)T_*B_*O_ + e) = o4;
  } else {
    *(float4*)((float*)out + (size_t)T_*B_*O_ + e) = v;
  }
}

extern "C" void kernel_launch(void* const* d_in, const int* in_sizes, int n_in,
                              void* d_out, int out_size, void* d_ws, size_t ws_size,
                              hipStream_t stream)
{
  const void* x  = d_in[0];
  const void* hs = d_in[1];
  const void* Wx = d_in[2];
  const void* Wh = d_in[3];
  const void* bv = d_in[4];
  const void* Wo = d_in[5];
  const void* bo = d_in[6];
  const void* mp = d_in[7];
  void* out = d_out;

  probe_dtype<<<dim3(1), dim3(64), 0, stream>>>((const u16*)x);
  prep_x     <<<dim3(8192), dim3(256), 0, stream>>>(x);
  prep_pack_g<<<dim3(2304), dim3(256), 0, stream>>>(Wx, Wh);
  prep_pack_o<<<dim3(256),  dim3(256), 0, stream>>>(Wo);
  prep_ring  <<<dim3(512),  dim3(256), 0, stream>>>(hs);
  gx_gemm    <<<dim3(1024), dim3(1024), 0, stream>>>(bv);

  void* args[] = { (void*)&mp };
  hipError_t err = hipLaunchCooperativeKernel(
      reinterpret_cast<const void*>(&mgruf_loop),
      dim3(NLBN), dim3(512), args, 0u, stream);
  if (err != hipSuccess) {
    for (int t = 0; t < T_; t++)
      mgruf_loop_step<<<dim3(NLB), dim3(512), 0, stream>>>(t, mp);
  }

  out_gemm   <<<dim3(256), dim3(1024), 0, stream>>>(bo, out);
  hfin_kernel<<<dim3(512), dim3(256), 0, stream>>>(out);
}